// Round 1
// baseline (304.539 us; speedup 1.0000x reference)
//
#include <hip/hip_runtime.h>
#include <math.h>

#define DEV static __device__ __forceinline__

typedef __attribute__((ext_vector_type(4))) float f32x4;
typedef __attribute__((ext_vector_type(8))) __bf16 bf16x8;
typedef __attribute__((ext_vector_type(8))) unsigned short u16x8;

constexpr int TB = 2;     // batch
constexpr int TT = 2048;  // seq len
constexpr int DM = 1024;  // model dim
constexpr int NH = 16;    // heads
constexpr int DH = 64;    // head dim
constexpr int MR = TB * TT;  // 4096 rows

DEV unsigned short f2bf(float f) {
  union { float f; unsigned u; } v; v.f = f;
  return (unsigned short)((v.u + 0x7FFFu + ((v.u >> 16) & 1u)) >> 16);
}

DEV void gld16(const void* g, void* l) {
  __builtin_amdgcn_global_load_lds((const __attribute__((address_space(1))) void*)g,
                                   (__attribute__((address_space(3))) void*)l, 16, 0, 0);
}

DEV bf16x8 ldsb8(const unsigned short* p) { return *(const bf16x8*)p; }

// ---------- fp32 -> bf16 convert (n multiple of 8) ----------
__global__ void k_cvt(const float* __restrict__ in, unsigned short* __restrict__ out, int n) {
  int i = (blockIdx.x * 256 + threadIdx.x) * 8;
  if (i >= n) return;
  f32x4 a = *(const f32x4*)(in + i);
  f32x4 b = *(const f32x4*)(in + i + 4);
  u16x8 o;
#pragma unroll
  for (int j = 0; j < 4; ++j) { o[j] = f2bf(a[j]); o[j + 4] = f2bf(b[j]); }
  *(u16x8*)(out + i) = o;
}

// ---------- weight fp32 [K][N] -> bf16 transposed [N][K] ----------
__global__ void k_wt(const float* __restrict__ w, unsigned short* __restrict__ wt) {
  __shared__ float tile[32][33];
  const int k0 = blockIdx.y * 32, n0 = blockIdx.x * 32;
  const int tx = threadIdx.x, ty = threadIdx.y;  // 32 x 8
#pragma unroll
  for (int yy = 0; yy < 32; yy += 8)
    tile[ty + yy][tx] = w[(size_t)(k0 + ty + yy) * DM + n0 + tx];
  __syncthreads();
#pragma unroll
  for (int yy = 0; yy < 32; yy += 8)
    wt[(size_t)(n0 + ty + yy) * DM + k0 + tx] = f2bf(tile[tx][ty + yy]);
}

// ---------- V [MR][DM] bf16 -> Vt [TB*NH][DH][TT] bf16 ----------
__global__ void k_vt(const unsigned short* __restrict__ V, unsigned short* __restrict__ Vt) {
  __shared__ unsigned short tile[32][33];
  const int bh = blockIdx.z, b = bh >> 4, h = bh & 15;
  const int t0 = blockIdx.x * 32, d0 = blockIdx.y * 32;
  const int tx = threadIdx.x, ty = threadIdx.y;
#pragma unroll
  for (int yy = 0; yy < 32; yy += 8)
    tile[ty + yy][tx] = V[(size_t)(b * TT + t0 + ty + yy) * DM + h * DH + d0 + tx];
  __syncthreads();
#pragma unroll
  for (int yy = 0; yy < 32; yy += 8)
    Vt[(size_t)(bh * DH + d0 + ty + yy) * TT + t0 + tx] = tile[tx][ty + yy];
}

// ---------- NT GEMM: C[M][N] = A[M][K] * Bt[N][K]^T, bf16 in, fp32 acc ----------
DEV void store_c(float* p, float v) { *p = v; }
DEV void store_c(unsigned short* p, float v) { *p = f2bf(v); }

template <typename OUT_T>
__global__ __launch_bounds__(256) void k_gemm_nt(const unsigned short* __restrict__ A,
                                                 const unsigned short* __restrict__ Bt,
                                                 OUT_T* __restrict__ C, int M, int N, int K) {
  __shared__ alignas(16) unsigned short As[128 * 32];
  __shared__ alignas(16) unsigned short Bs[128 * 32];
  const int tid = threadIdx.x;
  const int m0 = blockIdx.y * 128, n0 = blockIdx.x * 128;
  const int lane = tid & 63, w = tid >> 6;
  const int lr = lane & 15, lg = lane >> 4;
  const int wm = w >> 1, wn = w & 1;
  f32x4 acc[4][4] = {};
  for (int k0 = 0; k0 < K; k0 += 32) {
#pragma unroll
    for (int j = 0; j < 2; ++j) {
      int ci = j * 256 + tid;  // 512 x 16B chunks per tile; 4 chunks per 32-elem row
      gld16(A + (size_t)(m0 + (ci >> 2)) * K + k0 + (ci & 3) * 8, (void*)(As + ci * 8));
      gld16(Bt + (size_t)(n0 + (ci >> 2)) * K + k0 + (ci & 3) * 8, (void*)(Bs + ci * 8));
    }
    __syncthreads();
    bf16x8 af[4], bfr[4];
#pragma unroll
    for (int i = 0; i < 4; ++i) af[i] = ldsb8(As + (wm * 64 + i * 16 + lr) * 32 + lg * 8);
#pragma unroll
    for (int j = 0; j < 4; ++j) bfr[j] = ldsb8(Bs + (wn * 64 + j * 16 + lr) * 32 + lg * 8);
#pragma unroll
    for (int i = 0; i < 4; ++i)
#pragma unroll
      for (int j = 0; j < 4; ++j)
        acc[i][j] = __builtin_amdgcn_mfma_f32_16x16x32_bf16(af[i], bfr[j], acc[i][j], 0, 0, 0);
    __syncthreads();
  }
#pragma unroll
  for (int i = 0; i < 4; ++i)
#pragma unroll
    for (int j = 0; j < 4; ++j) {
      const int row = m0 + wm * 64 + i * 16 + lg * 4;
      const int col = n0 + wn * 64 + j * 16 + lr;
#pragma unroll
      for (int r = 0; r < 4; ++r) store_c(C + (size_t)(row + r) * N + col, acc[i][j][r]);
    }
}

// ---------- causal flash attention ----------
// grid (T/64, H, B); 4 waves, each owns 16 q-rows. KV tiles of 32.
__global__ __launch_bounds__(256) void k_attn(const unsigned short* __restrict__ Q,
                                              const unsigned short* __restrict__ K,
                                              const unsigned short* __restrict__ Vt,
                                              unsigned short* __restrict__ O) {
  __shared__ alignas(16) unsigned short Ks[32 * 64];     // [s][d]
  __shared__ alignas(16) unsigned short Vs[64 * 32];     // [d][s]
  __shared__ alignas(16) unsigned short Ps[4][16 * 32];  // per-wave P [q][s]
  const int b = blockIdx.z, h = blockIdx.y, q0 = blockIdx.x * 64;
  const int tid = threadIdx.x, lane = tid & 63, w = tid >> 6;
  const int lr = lane & 15, lg = lane >> 4;
  const int qw = q0 + w * 16;
  bf16x8 qf[2];
#pragma unroll
  for (int c = 0; c < 2; ++c)
    qf[c] = *(const bf16x8*)(Q + (size_t)(b * TT + qw + lr) * DM + h * DH + c * 32 + lg * 8);
  f32x4 acco[4] = {};
  float m[4], l[4];
#pragma unroll
  for (int r = 0; r < 4; ++r) { m[r] = -1e30f; l[r] = 0.f; }
  const unsigned short* Kg = K + (size_t)b * TT * DM + h * DH;
  const unsigned short* Vg = Vt + (size_t)(b * NH + h) * DH * TT;
  const int nt = (q0 + 64) / 32;
  for (int it = 0; it < nt; ++it) {
    const int s0 = it * 32;
    gld16(Kg + (size_t)(s0 + (tid >> 3)) * DM + (tid & 7) * 8, (void*)(Ks + tid * 8));
    gld16(Vg + (size_t)(tid >> 2) * TT + s0 + (tid & 3) * 8, (void*)(Vs + tid * 8));
    __syncthreads();
    // S = Q K^T  (rows q, cols s)
    f32x4 accs[2] = {};
#pragma unroll
    for (int ct = 0; ct < 2; ++ct)
#pragma unroll
      for (int c = 0; c < 2; ++c) {
        bf16x8 kf = ldsb8(Ks + (ct * 16 + lr) * 64 + c * 32 + lg * 8);
        accs[ct] = __builtin_amdgcn_mfma_f32_16x16x32_bf16(qf[c], kf, accs[ct], 0, 0, 0);
      }
    float p0[4], p1[4], aa[4];
#pragma unroll
    for (int r = 0; r < 4; ++r) {
      const int q = qw + lg * 4 + r;
      float sv0 = accs[0][r] * 0.125f;
      float sv1 = accs[1][r] * 0.125f;
      if (s0 + lr > q) sv0 = -1e30f;
      if (s0 + 16 + lr > q) sv1 = -1e30f;
      float mx = fmaxf(sv0, sv1);
      mx = fmaxf(mx, __shfl_xor(mx, 1));
      mx = fmaxf(mx, __shfl_xor(mx, 2));
      mx = fmaxf(mx, __shfl_xor(mx, 4));
      mx = fmaxf(mx, __shfl_xor(mx, 8));
      const float mn = fmaxf(m[r], mx);
      aa[r] = __expf(m[r] - mn);
      p0[r] = __expf(sv0 - mn);
      p1[r] = __expf(sv1 - mn);
      float rs = p0[r] + p1[r];
      rs += __shfl_xor(rs, 1);
      rs += __shfl_xor(rs, 2);
      rs += __shfl_xor(rs, 4);
      rs += __shfl_xor(rs, 8);
      l[r] = l[r] * aa[r] + rs;
      m[r] = mn;
    }
#pragma unroll
    for (int dt = 0; dt < 4; ++dt)
#pragma unroll
      for (int r = 0; r < 4; ++r) acco[dt][r] *= aa[r];
    // P -> LDS (per-wave region; same-wave DS ops stay ordered)
    unsigned short* Pw = Ps[w];
#pragma unroll
    for (int r = 0; r < 4; ++r) {
      Pw[(lg * 4 + r) * 32 + lr] = f2bf(p0[r]);
      Pw[(lg * 4 + r) * 32 + 16 + lr] = f2bf(p1[r]);
    }
    bf16x8 pf = ldsb8(Pw + lr * 32 + lg * 8);
#pragma unroll
    for (int dt = 0; dt < 4; ++dt) {
      bf16x8 vf = ldsb8(Vs + (dt * 16 + lr) * 32 + lg * 8);
      acco[dt] = __builtin_amdgcn_mfma_f32_16x16x32_bf16(pf, vf, acco[dt], 0, 0, 0);
    }
    __syncthreads();
  }
#pragma unroll
  for (int dt = 0; dt < 4; ++dt)
#pragma unroll
    for (int r = 0; r < 4; ++r) {
      const int q = qw + lg * 4 + r;
      O[(size_t)(b * TT + q) * DM + h * DH + dt * 16 + lr] = f2bf(acco[dt][r] / l[r]);
    }
}

extern "C" void kernel_launch(void* const* d_in, const int* in_sizes, int n_in,
                              void* d_out, int out_size, void* d_ws, size_t ws_size,
                              hipStream_t stream) {
  const float* x = (const float*)d_in[0];
  const float* wq = (const float*)d_in[1];
  const float* wk = (const float*)d_in[2];
  const float* wv = (const float*)d_in[3];
  const float* wo = (const float*)d_in[4];
  float* out = (float*)d_out;
  char* ws = (char*)d_ws;
  const size_t MB = 1u << 20;
  // ws layout (48 MB total, bf16):
  unsigned short* xb = (unsigned short*)(ws);            // 8MB; reused as attn-out
  unsigned short* wqt = (unsigned short*)(ws + 8 * MB);  // 2MB each
  unsigned short* wkt = (unsigned short*)(ws + 10 * MB);
  unsigned short* wvt = (unsigned short*)(ws + 12 * MB);
  unsigned short* wot = (unsigned short*)(ws + 14 * MB);
  unsigned short* Qb = (unsigned short*)(ws + 16 * MB);   // 8MB
  unsigned short* Kb = (unsigned short*)(ws + 24 * MB);   // 8MB
  unsigned short* Vb = (unsigned short*)(ws + 32 * MB);   // 8MB
  unsigned short* Vtb = (unsigned short*)(ws + 40 * MB);  // 8MB

  k_cvt<<<(MR * DM) / (256 * 8), 256, 0, stream>>>(x, xb, MR * DM);
  dim3 tb(32, 8);
  k_wt<<<dim3(32, 32), tb, 0, stream>>>(wq, wqt);
  k_wt<<<dim3(32, 32), tb, 0, stream>>>(wk, wkt);
  k_wt<<<dim3(32, 32), tb, 0, stream>>>(wv, wvt);
  k_wt<<<dim3(32, 32), tb, 0, stream>>>(wo, wot);
  k_gemm_nt<unsigned short><<<dim3(8, 32), 256, 0, stream>>>(xb, wqt, Qb, MR, DM, DM);
  k_gemm_nt<unsigned short><<<dim3(8, 32), 256, 0, stream>>>(xb, wkt, Kb, MR, DM, DM);
  k_gemm_nt<unsigned short><<<dim3(8, 32), 256, 0, stream>>>(xb, wvt, Vb, MR, DM, DM);
  k_vt<<<dim3(TT / 32, DH / 32, TB * NH), tb, 0, stream>>>(Vb, Vtb);
  k_attn<<<dim3(TT / 64, NH, TB), 256, 0, stream>>>(Qb, Kb, Vtb, xb);
  k_gemm_nt<float><<<dim3(8, 32), 256, 0, stream>>>(xb, wot, out, MR, DM, DM);
}

// Round 2
// 198.092 us; speedup vs baseline: 1.5374x; 1.5374x over previous
//
#include <hip/hip_runtime.h>
#include <math.h>

#define DEV static __device__ __forceinline__

typedef __attribute__((ext_vector_type(4))) float f32x4;
typedef __attribute__((ext_vector_type(8))) __bf16 bf16x8;
typedef __attribute__((ext_vector_type(8))) unsigned short u16x8;

constexpr int TB = 2;     // batch
constexpr int TT = 2048;  // seq len
constexpr int DM = 1024;  // model dim
constexpr int NH = 16;    // heads
constexpr int DH = 64;    // head dim
constexpr int MR = TB * TT;  // 4096 rows
constexpr int SQKV = 3 * DM; // fused QKV row stride

DEV unsigned short f2bf(float f) {
  union { float f; unsigned u; } v; v.f = f;
  return (unsigned short)((v.u + 0x7FFFu + ((v.u >> 16) & 1u)) >> 16);
}

DEV void gld16(const void* g, void* l) {
  __builtin_amdgcn_global_load_lds((const __attribute__((address_space(1))) void*)g,
                                   (__attribute__((address_space(3))) void*)l, 16, 0, 0);
}

DEV bf16x8 ldsb8(const unsigned short* p) { return *(const bf16x8*)p; }

// ---------- fp32 -> bf16 convert (n multiple of 8) ----------
__global__ void k_cvt(const float* __restrict__ in, unsigned short* __restrict__ out, int n) {
  int i = (blockIdx.x * 256 + threadIdx.x) * 8;
  if (i >= n) return;
  f32x4 a = *(const f32x4*)(in + i);
  f32x4 b = *(const f32x4*)(in + i + 4);
  u16x8 o;
#pragma unroll
  for (int j = 0; j < 4; ++j) { o[j] = f2bf(a[j]); o[j + 4] = f2bf(b[j]); }
  *(u16x8*)(out + i) = o;
}

// ---------- 4 weights fp32 [K][N] -> bf16 transposed [N][K], contiguous dst ----------
__global__ void k_wt4(const float* __restrict__ w0, const float* __restrict__ w1,
                      const float* __restrict__ w2, const float* __restrict__ w3,
                      unsigned short* __restrict__ dst) {
  __shared__ float tile[32][33];
  const int z = blockIdx.z;
  const float* w = z == 0 ? w0 : z == 1 ? w1 : z == 2 ? w2 : w3;
  unsigned short* wt = dst + (size_t)z * DM * DM;
  const int k0 = blockIdx.y * 32, n0 = blockIdx.x * 32;
  const int tx = threadIdx.x, ty = threadIdx.y;  // 32 x 8
#pragma unroll
  for (int yy = 0; yy < 32; yy += 8)
    tile[ty + yy][tx] = w[(size_t)(k0 + ty + yy) * DM + n0 + tx];
  __syncthreads();
#pragma unroll
  for (int yy = 0; yy < 32; yy += 8)
    wt[(size_t)(n0 + ty + yy) * DM + k0 + tx] = f2bf(tile[tx][ty + yy]);
}

// ---------- V (inside QKV, stride SQKV) -> Vt [TB*NH][DH][TT] bf16 ----------
__global__ void k_vt(const unsigned short* __restrict__ V, unsigned short* __restrict__ Vt) {
  __shared__ unsigned short tile[32][33];
  const int bh = blockIdx.z, b = bh >> 4, h = bh & 15;
  const int t0 = blockIdx.x * 32, d0 = blockIdx.y * 32;
  const int tx = threadIdx.x, ty = threadIdx.y;
#pragma unroll
  for (int yy = 0; yy < 32; yy += 8)
    tile[ty + yy][tx] = V[(size_t)(b * TT + t0 + ty + yy) * SQKV + h * DH + d0 + tx];
  __syncthreads();
#pragma unroll
  for (int yy = 0; yy < 32; yy += 8)
    Vt[(size_t)(bh * DH + d0 + ty + yy) * TT + t0 + tx] = tile[tx][ty + yy];
}

// ---------- NT GEMM: C[M][N] = A[M][K] * Bt[N][K]^T, bf16 in, fp32 acc ----------
DEV void store_c(float* p, float v) { *p = v; }
DEV void store_c(unsigned short* p, float v) { *p = f2bf(v); }

template <typename OUT_T>
__global__ __launch_bounds__(256) void k_gemm_nt(const unsigned short* __restrict__ A,
                                                 const unsigned short* __restrict__ Bt,
                                                 OUT_T* __restrict__ C, int M, int N, int K) {
  __shared__ alignas(16) unsigned short As[128 * 32];
  __shared__ alignas(16) unsigned short Bs[128 * 32];
  const int tid = threadIdx.x;
  const int m0 = blockIdx.y * 128, n0 = blockIdx.x * 128;
  const int lane = tid & 63, w = tid >> 6;
  const int lr = lane & 15, lg = lane >> 4;
  const int wm = w >> 1, wn = w & 1;
  f32x4 acc[4][4] = {};
  for (int k0 = 0; k0 < K; k0 += 32) {
#pragma unroll
    for (int j = 0; j < 2; ++j) {
      int ci = j * 256 + tid;
      gld16(A + (size_t)(m0 + (ci >> 2)) * K + k0 + (ci & 3) * 8, (void*)(As + ci * 8));
      gld16(Bt + (size_t)(n0 + (ci >> 2)) * K + k0 + (ci & 3) * 8, (void*)(Bs + ci * 8));
    }
    __syncthreads();
    bf16x8 af[4], bfr[4];
#pragma unroll
    for (int i = 0; i < 4; ++i) af[i] = ldsb8(As + (wm * 64 + i * 16 + lr) * 32 + lg * 8);
#pragma unroll
    for (int j = 0; j < 4; ++j) bfr[j] = ldsb8(Bs + (wn * 64 + j * 16 + lr) * 32 + lg * 8);
#pragma unroll
    for (int i = 0; i < 4; ++i)
#pragma unroll
      for (int j = 0; j < 4; ++j)
        acc[i][j] = __builtin_amdgcn_mfma_f32_16x16x32_bf16(af[i], bfr[j], acc[i][j], 0, 0, 0);
    __syncthreads();
  }
#pragma unroll
  for (int i = 0; i < 4; ++i)
#pragma unroll
    for (int j = 0; j < 4; ++j) {
      const int row = m0 + wm * 64 + i * 16 + lg * 4;
      const int col = n0 + wn * 64 + j * 16 + lr;
#pragma unroll
      for (int r = 0; r < 4; ++r) store_c(C + (size_t)(row + r) * N + col, acc[i][j][r]);
    }
}

// ---------- causal flash attention v2 ----------
// grid (T/128, H, B); 4 waves x 32 q-rows; KV tiles of 64, double-buffered,
// XOR-swizzled LDS (linear gld16 dest + inverse-swizzled global source).
__global__ __launch_bounds__(256) void k_attn2(const unsigned short* __restrict__ QKV,
                                               const unsigned short* __restrict__ Vt,
                                               unsigned short* __restrict__ O) {
  __shared__ alignas(16) unsigned short Ks[2][64 * 64];  // [s][d] swizzled
  __shared__ alignas(16) unsigned short Vs[2][64 * 64];  // [d][s] swizzled
  __shared__ alignas(16) unsigned short Ps[4][32 * 64];  // per-wave P [q][s] swizzled
  const int b = blockIdx.z, h = blockIdx.y, q0 = blockIdx.x * 128;
  const int tid = threadIdx.x, lane = tid & 63, w = tid >> 6;
  const int lr = lane & 15, lg = lane >> 4;
  const int lsw = lr & 7;  // read-side XOR key
  const int qw = q0 + w * 32;
  const unsigned short* Qg = QKV + (size_t)b * TT * SQKV + h * DH;
  const unsigned short* Kg = QKV + (size_t)b * TT * SQKV + DM + h * DH;
  const unsigned short* Vg = Vt + (size_t)(b * NH + h) * DH * TT;
  unsigned short* Pw = Ps[w];

  bf16x8 qf[2][2];
#pragma unroll
  for (int qi = 0; qi < 2; ++qi)
#pragma unroll
    for (int c = 0; c < 2; ++c)
      qf[qi][c] = *(const bf16x8*)(Qg + (size_t)(qw + qi * 16 + lr) * SQKV + c * 32 + lg * 8);

  f32x4 acco[2][4] = {};
  float m[2][4], l[2][4];
#pragma unroll
  for (int qi = 0; qi < 2; ++qi)
#pragma unroll
    for (int r = 0; r < 4; ++r) { m[qi][r] = -1e30f; l[qi][r] = 0.f; }

  // stage one KV tile: 512 x 16B chunks each for K and V; source pre-swizzled
  auto stage = [&](int buf, int t) {
    const int s0 = t * 64;
#pragma unroll
    for (int j = 0; j < 2; ++j) {
      const int ci = j * 256 + tid;
      const int row = ci >> 3, cc = (ci & 7) ^ (row & 7);
      gld16(Kg + (size_t)(s0 + row) * SQKV + cc * 8, (void*)(Ks[buf] + ci * 8));
      gld16(Vg + (size_t)row * TT + s0 + cc * 8, (void*)(Vs[buf] + ci * 8));
    }
  };

  const int nt = q0 / 64 + 2;
  stage(0, 0);
  for (int t = 0; t < nt; ++t) {
    const int buf = t & 1;
    if (t + 1 < nt) {
      stage(buf ^ 1, t + 1);
      asm volatile("s_waitcnt vmcnt(4)" ::: "memory");  // tile t landed; t+1 in flight
    } else {
      asm volatile("s_waitcnt vmcnt(0)" ::: "memory");
    }
    __builtin_amdgcn_s_barrier();
    const unsigned short* Kb_ = Ks[buf];
    const unsigned short* Vb_ = Vs[buf];
    const int s0 = t * 64;
    // ---- S = Q K^T ----
    f32x4 accs[2][4] = {};
#pragma unroll
    for (int ct = 0; ct < 4; ++ct) {
      const int ro = ct * 16 + lr;
#pragma unroll
      for (int c = 0; c < 2; ++c) {
        bf16x8 kf = ldsb8(Kb_ + ro * 64 + (((c * 4 + lg) ^ lsw) * 8));
#pragma unroll
        for (int qi = 0; qi < 2; ++qi)
          accs[qi][ct] = __builtin_amdgcn_mfma_f32_16x16x32_bf16(qf[qi][c], kf, accs[qi][ct], 0, 0, 0);
      }
    }
    // ---- online softmax (rows q, 64 s-vals spread over 4 regs x 16 lanes) ----
    float aa[2][4];
#pragma unroll
    for (int qi = 0; qi < 2; ++qi)
#pragma unroll
      for (int r = 0; r < 4; ++r) {
        const int q = qw + qi * 16 + lg * 4 + r;
        float sv[4];
#pragma unroll
        for (int ct = 0; ct < 4; ++ct) {
          sv[ct] = accs[qi][ct][r] * 0.125f;
          if (s0 + ct * 16 + lr > q) sv[ct] = -1e30f;
        }
        float mx = fmaxf(fmaxf(sv[0], sv[1]), fmaxf(sv[2], sv[3]));
        mx = fmaxf(mx, __shfl_xor(mx, 1));
        mx = fmaxf(mx, __shfl_xor(mx, 2));
        mx = fmaxf(mx, __shfl_xor(mx, 4));
        mx = fmaxf(mx, __shfl_xor(mx, 8));
        const float mn = fmaxf(m[qi][r], mx);
        aa[qi][r] = __expf(m[qi][r] - mn);
        m[qi][r] = mn;
        float rs = 0.f;
#pragma unroll
        for (int ct = 0; ct < 4; ++ct) { sv[ct] = __expf(sv[ct] - mn); rs += sv[ct]; }
        rs += __shfl_xor(rs, 1);
        rs += __shfl_xor(rs, 2);
        rs += __shfl_xor(rs, 4);
        rs += __shfl_xor(rs, 8);
        l[qi][r] = l[qi][r] * aa[qi][r] + rs;
        // P -> per-wave LDS (swizzled): row = qi*16+lg*4+r, col = ct*16+lr
        const int qa = (lg * 4 + r) & 7;
#pragma unroll
        for (int ct = 0; ct < 4; ++ct)
          Pw[(qi * 16 + lg * 4 + r) * 64 + (((ct * 2 + (lr >> 3)) ^ qa) * 8) + (lr & 7)] = f2bf(sv[ct]);
      }
    // rescale O
#pragma unroll
    for (int qi = 0; qi < 2; ++qi)
#pragma unroll
      for (int dt = 0; dt < 4; ++dt)
#pragma unroll
        for (int r = 0; r < 4; ++r) acco[qi][dt][r] *= aa[qi][r];
    // ---- O += P V^T ----
    bf16x8 pf[2][2];
#pragma unroll
    for (int qi = 0; qi < 2; ++qi)
#pragma unroll
      for (int ks = 0; ks < 2; ++ks)
        pf[qi][ks] = ldsb8(Pw + (qi * 16 + lr) * 64 + (((ks * 4 + lg) ^ lsw) * 8));
#pragma unroll
    for (int dt = 0; dt < 4; ++dt)
#pragma unroll
      for (int ks = 0; ks < 2; ++ks) {
        bf16x8 vf = ldsb8(Vb_ + (dt * 16 + lr) * 64 + (((ks * 4 + lg) ^ lsw) * 8));
#pragma unroll
        for (int qi = 0; qi < 2; ++qi)
          acco[qi][dt] = __builtin_amdgcn_mfma_f32_16x16x32_bf16(pf[qi][ks], vf, acco[qi][dt], 0, 0, 0);
      }
    asm volatile("" ::: "memory");
    __builtin_amdgcn_s_barrier();  // protect buf before next stage overwrites it
  }
  // ---- epilogue ----
#pragma unroll
  for (int qi = 0; qi < 2; ++qi)
#pragma unroll
    for (int dt = 0; dt < 4; ++dt)
#pragma unroll
      for (int r = 0; r < 4; ++r) {
        const int q = qw + qi * 16 + lg * 4 + r;
        O[(size_t)(b * TT + q) * DM + h * DH + dt * 16 + lr] = f2bf(acco[qi][dt][r] / l[qi][r]);
      }
}

extern "C" void kernel_launch(void* const* d_in, const int* in_sizes, int n_in,
                              void* d_out, int out_size, void* d_ws, size_t ws_size,
                              hipStream_t stream) {
  const float* x = (const float*)d_in[0];
  const float* wq = (const float*)d_in[1];
  const float* wk = (const float*)d_in[2];
  const float* wv = (const float*)d_in[3];
  const float* wo = (const float*)d_in[4];
  float* out = (float*)d_out;
  char* ws = (char*)d_ws;
  const size_t MB = 1u << 20;
  // ws layout (48 MB):
  unsigned short* xb = (unsigned short*)(ws);             // 8MB: x bf16; reused as attn-out
  unsigned short* wqt = (unsigned short*)(ws + 8 * MB);   // 2MB x4 contiguous: wq^T wk^T wv^T wo^T
  unsigned short* wot = (unsigned short*)(ws + 14 * MB);
  unsigned short* QKVb = (unsigned short*)(ws + 16 * MB); // 24MB: [MR][3072]
  unsigned short* Vtb = (unsigned short*)(ws + 40 * MB);  // 8MB: [B*H][64][T]

  k_cvt<<<(MR * DM) / (256 * 8), 256, 0, stream>>>(x, xb, MR * DM);
  dim3 tb(32, 8);
  k_wt4<<<dim3(32, 32, 4), tb, 0, stream>>>(wq, wk, wv, wo, wqt);
  k_gemm_nt<unsigned short><<<dim3(24, 32), 256, 0, stream>>>(xb, wqt, QKVb, MR, SQKV, DM);
  k_vt<<<dim3(TT / 32, DH / 32, TB * NH), tb, 0, stream>>>(QKVb + 2 * DM, Vtb);
  k_attn2<<<dim3(TT / 128, NH, TB), 256, 0, stream>>>(QKVb, Vtb, xb);
  k_gemm_nt<float><<<dim3(8, 32), 256, 0, stream>>>(xb, wot, out, MR, DM, DM);
}

// Round 3
// 160.979 us; speedup vs baseline: 1.8918x; 1.2305x over previous
//
#include <hip/hip_runtime.h>
#include <math.h>

#define DEV static __device__ __forceinline__

typedef __attribute__((ext_vector_type(4))) float f32x4;
typedef __attribute__((ext_vector_type(2))) unsigned u32x2;
typedef __attribute__((ext_vector_type(8))) __bf16 bf16x8;
typedef __attribute__((ext_vector_type(8))) unsigned short u16x8;

constexpr int TB = 2;     // batch
constexpr int TT = 2048;  // seq len
constexpr int DM = 1024;  // model dim
constexpr int NH = 16;    // heads
constexpr int DH = 64;    // head dim
constexpr int MR = TB * TT;  // 4096 rows
constexpr int SQKV = 3 * DM; // fused QKV row stride

DEV unsigned short f2bf(float f) {
  union { float f; unsigned u; } v; v.f = f;
  return (unsigned short)((v.u + 0x7FFFu + ((v.u >> 16) & 1u)) >> 16);
}

DEV unsigned cvtpk(float a, float b) {  // lo=bf16(a), hi=bf16(b)
  unsigned r;
  asm("v_cvt_pk_bf16_f32 %0, %1, %2" : "=v"(r) : "v"(a), "v"(b));
  return r;
}

DEV void gld16(const void* g, void* l) {
  __builtin_amdgcn_global_load_lds((const __attribute__((address_space(1))) void*)g,
                                   (__attribute__((address_space(3))) void*)l, 16, 0, 0);
}

DEV bf16x8 ldsb8(const unsigned short* p) { return *(const bf16x8*)p; }

// ---------- fp32 -> bf16 convert (n multiple of 8) ----------
__global__ void k_cvt(const float* __restrict__ in, unsigned short* __restrict__ out, int n) {
  int i = (blockIdx.x * 256 + threadIdx.x) * 8;
  if (i >= n) return;
  f32x4 a = *(const f32x4*)(in + i);
  f32x4 b = *(const f32x4*)(in + i + 4);
  u16x8 o;
#pragma unroll
  for (int j = 0; j < 4; ++j) { o[j] = f2bf(a[j]); o[j + 4] = f2bf(b[j]); }
  *(u16x8*)(out + i) = o;
}

// ---------- 4 weights fp32 [K][N] -> bf16 transposed [N][K], contiguous dst ----------
__global__ void k_wt4(const float* __restrict__ w0, const float* __restrict__ w1,
                      const float* __restrict__ w2, const float* __restrict__ w3,
                      unsigned short* __restrict__ dst) {
  __shared__ float tile[32][33];
  const int z = blockIdx.z;
  const float* w = z == 0 ? w0 : z == 1 ? w1 : z == 2 ? w2 : w3;
  unsigned short* wt = dst + (size_t)z * DM * DM;
  const int k0 = blockIdx.y * 32, n0 = blockIdx.x * 32;
  const int tx = threadIdx.x, ty = threadIdx.y;  // 32 x 8
#pragma unroll
  for (int yy = 0; yy < 32; yy += 8)
    tile[ty + yy][tx] = w[(size_t)(k0 + ty + yy) * DM + n0 + tx];
  __syncthreads();
#pragma unroll
  for (int yy = 0; yy < 32; yy += 8)
    wt[(size_t)(n0 + ty + yy) * DM + k0 + tx] = f2bf(tile[tx][ty + yy]);
}

// ---------- V (inside QKV, stride SQKV) -> Vt [TB*NH][DH][TT] bf16 ----------
__global__ void k_vt(const unsigned short* __restrict__ V, unsigned short* __restrict__ Vt) {
  __shared__ unsigned short tile[32][33];
  const int bh = blockIdx.z, b = bh >> 4, h = bh & 15;
  const int t0 = blockIdx.x * 32, d0 = blockIdx.y * 32;
  const int tx = threadIdx.x, ty = threadIdx.y;
#pragma unroll
  for (int yy = 0; yy < 32; yy += 8)
    tile[ty + yy][tx] = V[(size_t)(b * TT + t0 + ty + yy) * SQKV + h * DH + d0 + tx];
  __syncthreads();
#pragma unroll
  for (int yy = 0; yy < 32; yy += 8)
    Vt[(size_t)(bh * DH + d0 + ty + yy) * TT + t0 + tx] = tile[tx][ty + yy];
}

// ---------- NT GEMM: C[M][N] = A[M][K] * Bt[N][K]^T, bf16 in, fp32 acc ----------
DEV void store_c(float* p, float v) { *p = v; }
DEV void store_c(unsigned short* p, float v) { *p = f2bf(v); }

template <typename OUT_T>
__global__ __launch_bounds__(256) void k_gemm_nt(const unsigned short* __restrict__ A,
                                                 const unsigned short* __restrict__ Bt,
                                                 OUT_T* __restrict__ C, int M, int N, int K) {
  __shared__ alignas(16) unsigned short As[128 * 32];
  __shared__ alignas(16) unsigned short Bs[128 * 32];
  const int tid = threadIdx.x;
  const int m0 = blockIdx.y * 128, n0 = blockIdx.x * 128;
  const int lane = tid & 63, w = tid >> 6;
  const int lr = lane & 15, lg = lane >> 4;
  const int wm = w >> 1, wn = w & 1;
  f32x4 acc[4][4] = {};
  for (int k0 = 0; k0 < K; k0 += 32) {
#pragma unroll
    for (int j = 0; j < 2; ++j) {
      int ci = j * 256 + tid;
      gld16(A + (size_t)(m0 + (ci >> 2)) * K + k0 + (ci & 3) * 8, (void*)(As + ci * 8));
      gld16(Bt + (size_t)(n0 + (ci >> 2)) * K + k0 + (ci & 3) * 8, (void*)(Bs + ci * 8));
    }
    __syncthreads();
    bf16x8 af[4], bfr[4];
#pragma unroll
    for (int i = 0; i < 4; ++i) af[i] = ldsb8(As + (wm * 64 + i * 16 + lr) * 32 + lg * 8);
#pragma unroll
    for (int j = 0; j < 4; ++j) bfr[j] = ldsb8(Bs + (wn * 64 + j * 16 + lr) * 32 + lg * 8);
#pragma unroll
    for (int i = 0; i < 4; ++i)
#pragma unroll
      for (int j = 0; j < 4; ++j)
        acc[i][j] = __builtin_amdgcn_mfma_f32_16x16x32_bf16(af[i], bfr[j], acc[i][j], 0, 0, 0);
    __syncthreads();
  }
#pragma unroll
  for (int i = 0; i < 4; ++i)
#pragma unroll
    for (int j = 0; j < 4; ++j) {
      const int row = m0 + wm * 64 + i * 16 + lg * 4;
      const int col = n0 + wn * 64 + j * 16 + lr;
#pragma unroll
      for (int r = 0; r < 4; ++r) store_c(C + (size_t)(row + r) * N + col, acc[i][j][r]);
    }
}

// ---------- causal flash attention v3 ----------
// grid (T/128, H, B); 8 waves x 16 q-rows; KV tiles of 64, double-buffered.
// Swapped QK^T (S^T in regs -> lane-local softmax), per-wave diag/full/skip paths.
__global__ __launch_bounds__(512, 4) void k_attn3(const unsigned short* __restrict__ QKV,
                                                  const unsigned short* __restrict__ Vt,
                                                  unsigned short* __restrict__ O) {
  __shared__ alignas(16) unsigned short Ks[2][64 * 64];  // [s][d] swizzled
  __shared__ alignas(16) unsigned short Vs[2][64 * 64];  // [d][s] swizzled
  __shared__ alignas(16) unsigned short Ps[8][16 * 64];  // per-wave P [q][s] swizzled
  const int b = blockIdx.z, h = blockIdx.y, q0 = blockIdx.x * 128;
  const int tid = threadIdx.x, lane = tid & 63, w = tid >> 6;
  const int lr = lane & 15, lg = lane >> 4;
  const int lsw = lr & 7;  // XOR key (row&7 for all our reads)
  const int qw = q0 + w * 16;
  const unsigned short* Qg = QKV + (size_t)b * TT * SQKV + h * DH;
  const unsigned short* Kg = QKV + (size_t)b * TT * SQKV + DM + h * DH;
  const unsigned short* Vg = Vt + (size_t)(b * NH + h) * DH * TT;
  unsigned short* Pw = Ps[w];

  // Q fragment (B-operand role): lane holds Q[qw+lr][c*32 + lg*8 ..]
  bf16x8 qf[2];
#pragma unroll
  for (int c = 0; c < 2; ++c)
    qf[c] = *(const bf16x8*)(Qg + (size_t)(qw + lr) * SQKV + c * 32 + lg * 8);

  f32x4 acco[4] = {};
  float mrun = -1e30f, lrun = 0.f;

  // stage one KV tile: 512 threads x 1 chunk each for K and V; source pre-swizzled
  auto stage = [&](int buf, int t) {
    const int s0 = t * 64;
    const int row = tid >> 3, cc = (tid & 7) ^ (row & 7);
    gld16(Kg + (size_t)(s0 + row) * SQKV + cc * 8, (void*)(Ks[buf] + tid * 8));
    gld16(Vg + (size_t)row * TT + s0 + cc * 8, (void*)(Vs[buf] + tid * 8));
  };

  const int nt = q0 / 64 + 2;
  stage(0, 0);
  for (int t = 0; t < nt; ++t) {
    const int buf = t & 1;
    if (t + 1 < nt) {
      stage(buf ^ 1, t + 1);
      asm volatile("s_waitcnt vmcnt(2)" ::: "memory");  // tile t landed; t+1 in flight
    } else {
      asm volatile("s_waitcnt vmcnt(0)" ::: "memory");
    }
    __builtin_amdgcn_s_barrier();
    const int s0 = t * 64;
    if (s0 <= qw + 15) {  // not fully masked for this wave
      const unsigned short* Kb_ = Ks[buf];
      const unsigned short* Vb_ = Vs[buf];
      // ---- S^T = K Q^T : st[ct] holds S[s=s0+ct*16+lg*4+r][q=qw+lr] ----
      f32x4 st[4] = {};
#pragma unroll
      for (int ct = 0; ct < 4; ++ct)
#pragma unroll
        for (int c = 0; c < 2; ++c) {
          bf16x8 kf = ldsb8(Kb_ + (ct * 16 + lr) * 64 + (((c * 4 + lg) ^ lsw) * 8));
          st[ct] = __builtin_amdgcn_mfma_f32_16x16x32_bf16(kf, qf[c], st[ct], 0, 0, 0);
        }
      // ---- lane-local softmax over 16 s-values (+2 shuffles across lg) ----
      constexpr float sc = 0.18033688f;  // 0.125 * log2(e)
      float p[4][4];
      const bool diag = (s0 + 63 >= qw);
      const int qrel = qw + lr - s0;
      float mx = -1e30f;
      if (diag) {
#pragma unroll
        for (int ct = 0; ct < 4; ++ct)
#pragma unroll
          for (int r = 0; r < 4; ++r) {
            float v = st[ct][r] * sc;
            if (ct * 16 + lg * 4 + r > qrel) v = -1e30f;
            p[ct][r] = v;
            mx = fmaxf(mx, v);
          }
      } else {
#pragma unroll
        for (int ct = 0; ct < 4; ++ct)
#pragma unroll
          for (int r = 0; r < 4; ++r) {
            float v = st[ct][r] * sc;
            p[ct][r] = v;
            mx = fmaxf(mx, v);
          }
      }
      mx = fmaxf(mx, __shfl_xor(mx, 16));
      mx = fmaxf(mx, __shfl_xor(mx, 32));
      const float mn = fmaxf(mrun, mx);
      const float aa = __builtin_exp2f(mrun - mn);
      mrun = mn;
      float rs = 0.f;
#pragma unroll
      for (int ct = 0; ct < 4; ++ct)
#pragma unroll
        for (int r = 0; r < 4; ++r) {
          p[ct][r] = __builtin_exp2f(p[ct][r] - mn);
          rs += p[ct][r];
        }
      rs += __shfl_xor(rs, 16);
      rs += __shfl_xor(rs, 32);
      lrun = lrun * aa + rs;
      // ---- P -> per-wave LDS: row=lr, s-range ct*16+lg*4..+3, b64 writes ----
#pragma unroll
      for (int ct = 0; ct < 4; ++ct) {
        u32x2 pk;
        pk[0] = cvtpk(p[ct][0], p[ct][1]);
        pk[1] = cvtpk(p[ct][2], p[ct][3]);
        *(u32x2*)(Pw + lr * 64 + (((ct * 2 + (lg >> 1)) ^ lsw) * 8) + (lg & 1) * 4) = pk;
      }
      // ---- rescale O (aa broadcast: acco row q = lg*4+r, aa lives at lane lr=q) ----
      float aab[4];
#pragma unroll
      for (int r = 0; r < 4; ++r) aab[r] = __shfl(aa, lg * 4 + r);
#pragma unroll
      for (int dt = 0; dt < 4; ++dt)
#pragma unroll
        for (int r = 0; r < 4; ++r) acco[dt][r] *= aab[r];
      // ---- O += P V^T ----
      bf16x8 pf[2];
#pragma unroll
      for (int ks = 0; ks < 2; ++ks)
        pf[ks] = ldsb8(Pw + lr * 64 + (((ks * 4 + lg) ^ lsw) * 8));
#pragma unroll
      for (int dt = 0; dt < 4; ++dt)
#pragma unroll
        for (int ks = 0; ks < 2; ++ks) {
          bf16x8 vf = ldsb8(Vb_ + (dt * 16 + lr) * 64 + (((ks * 4 + lg) ^ lsw) * 8));
          acco[dt] = __builtin_amdgcn_mfma_f32_16x16x32_bf16(pf[ks], vf, acco[dt], 0, 0, 0);
        }
    }
    __builtin_amdgcn_s_barrier();  // protect buf before next stage overwrites it
  }
  // ---- epilogue ----
  const float linv = 1.f / lrun;
  float lb[4];
#pragma unroll
  for (int r = 0; r < 4; ++r) lb[r] = __shfl(linv, lg * 4 + r);
#pragma unroll
  for (int dt = 0; dt < 4; ++dt)
#pragma unroll
    for (int r = 0; r < 4; ++r) {
      const int q = qw + lg * 4 + r;
      O[(size_t)(b * TT + q) * DM + h * DH + dt * 16 + lr] = f2bf(acco[dt][r] * lb[r]);
    }
}

extern "C" void kernel_launch(void* const* d_in, const int* in_sizes, int n_in,
                              void* d_out, int out_size, void* d_ws, size_t ws_size,
                              hipStream_t stream) {
  const float* x = (const float*)d_in[0];
  const float* wq = (const float*)d_in[1];
  const float* wk = (const float*)d_in[2];
  const float* wv = (const float*)d_in[3];
  const float* wo = (const float*)d_in[4];
  float* out = (float*)d_out;
  char* ws = (char*)d_ws;
  const size_t MB = 1u << 20;
  // ws layout (48 MB):
  unsigned short* xb = (unsigned short*)(ws);             // 8MB: x bf16; reused as attn-out
  unsigned short* wqt = (unsigned short*)(ws + 8 * MB);   // 2MB x4 contiguous: wq^T wk^T wv^T wo^T
  unsigned short* wot = (unsigned short*)(ws + 14 * MB);
  unsigned short* QKVb = (unsigned short*)(ws + 16 * MB); // 24MB: [MR][3072]
  unsigned short* Vtb = (unsigned short*)(ws + 40 * MB);  // 8MB: [B*H][64][T]

  k_cvt<<<(MR * DM) / (256 * 8), 256, 0, stream>>>(x, xb, MR * DM);
  dim3 tb(32, 8);
  k_wt4<<<dim3(32, 32, 4), tb, 0, stream>>>(wq, wk, wv, wo, wqt);
  k_gemm_nt<unsigned short><<<dim3(24, 32), 256, 0, stream>>>(xb, wqt, QKVb, MR, SQKV, DM);
  k_vt<<<dim3(TT / 32, DH / 32, TB * NH), tb, 0, stream>>>(QKVb + 2 * DM, Vtb);
  k_attn3<<<dim3(TT / 128, NH, TB), 512, 0, stream>>>(QKVb, Vtb, xb);
  k_gemm_nt<float><<<dim3(8, 32), 256, 0, stream>>>(xb, wot, out, MR, DM, DM);
}

// Round 4
// 155.869 us; speedup vs baseline: 1.9538x; 1.0328x over previous
//
#include <hip/hip_runtime.h>
#include <math.h>

#define DEV static __device__ __forceinline__

typedef __attribute__((ext_vector_type(4))) float f32x4;
typedef __attribute__((ext_vector_type(2))) unsigned u32x2;
typedef __attribute__((ext_vector_type(8))) __bf16 bf16x8;
typedef __attribute__((ext_vector_type(8))) unsigned short u16x8;

constexpr int TB = 2;     // batch
constexpr int TT = 2048;  // seq len
constexpr int DM = 1024;  // model dim
constexpr int NH = 16;    // heads
constexpr int DH = 64;    // head dim
constexpr int MR = TB * TT;  // 4096 rows
constexpr int SQKV = 3 * DM; // fused QKV row stride

DEV unsigned short f2bf(float f) {
  union { float f; unsigned u; } v; v.f = f;
  return (unsigned short)((v.u + 0x7FFFu + ((v.u >> 16) & 1u)) >> 16);
}

DEV unsigned cvtpk(float a, float b) {  // lo=bf16(a), hi=bf16(b)
  unsigned r;
  asm("v_cvt_pk_bf16_f32 %0, %1, %2" : "=v"(r) : "v"(a), "v"(b));
  return r;
}

DEV void gld16(const void* g, void* l) {
  __builtin_amdgcn_global_load_lds((const __attribute__((address_space(1))) void*)g,
                                   (__attribute__((address_space(3))) void*)l, 16, 0, 0);
}

DEV bf16x8 ldsb8(const unsigned short* p) { return *(const bf16x8*)p; }

// ---------- fp32 -> bf16 convert (n multiple of 8) ----------
__global__ void k_cvt(const float* __restrict__ in, unsigned short* __restrict__ out, int n) {
  int i = (blockIdx.x * 256 + threadIdx.x) * 8;
  if (i >= n) return;
  f32x4 a = *(const f32x4*)(in + i);
  f32x4 b = *(const f32x4*)(in + i + 4);
  u16x8 o;
#pragma unroll
  for (int j = 0; j < 4; ++j) { o[j] = f2bf(a[j]); o[j + 4] = f2bf(b[j]); }
  *(u16x8*)(out + i) = o;
}

// ---------- 4 weights fp32 [K][N] -> bf16 transposed [N][K], contiguous dst ----------
__global__ void k_wt4(const float* __restrict__ w0, const float* __restrict__ w1,
                      const float* __restrict__ w2, const float* __restrict__ w3,
                      unsigned short* __restrict__ dst) {
  __shared__ float tile[32][33];
  const int z = blockIdx.z;
  const float* w = z == 0 ? w0 : z == 1 ? w1 : z == 2 ? w2 : w3;
  unsigned short* wt = dst + (size_t)z * DM * DM;
  const int k0 = blockIdx.y * 32, n0 = blockIdx.x * 32;
  const int tx = threadIdx.x, ty = threadIdx.y;  // 32 x 8
#pragma unroll
  for (int yy = 0; yy < 32; yy += 8)
    tile[ty + yy][tx] = w[(size_t)(k0 + ty + yy) * DM + n0 + tx];
  __syncthreads();
#pragma unroll
  for (int yy = 0; yy < 32; yy += 8)
    wt[(size_t)(n0 + ty + yy) * DM + k0 + tx] = f2bf(tile[tx][ty + yy]);
}

// ---------- V (inside QKV, stride SQKV) -> Vt [TB*NH][DH][TT] bf16 ----------
__global__ void k_vt(const unsigned short* __restrict__ V, unsigned short* __restrict__ Vt) {
  __shared__ unsigned short tile[32][33];
  const int bh = blockIdx.z, b = bh >> 4, h = bh & 15;
  const int t0 = blockIdx.x * 32, d0 = blockIdx.y * 32;
  const int tx = threadIdx.x, ty = threadIdx.y;
#pragma unroll
  for (int yy = 0; yy < 32; yy += 8)
    tile[ty + yy][tx] = V[(size_t)(b * TT + t0 + ty + yy) * SQKV + h * DH + d0 + tx];
  __syncthreads();
#pragma unroll
  for (int yy = 0; yy < 32; yy += 8)
    Vt[(size_t)(bh * DH + d0 + ty + yy) * TT + t0 + tx] = tile[tx][ty + yy];
}

// ---------- NT GEMM: C[M][N] = A[M][K] * Bt[N][K]^T, bf16 in, fp32 acc ----------
// Columns col < scol get scaled by ascale on store (used to pre-scale Q).
DEV void store_c(float* p, float v) { *p = v; }
DEV void store_c(unsigned short* p, float v) { *p = f2bf(v); }

template <typename OUT_T>
__global__ __launch_bounds__(256) void k_gemm_nt(const unsigned short* __restrict__ A,
                                                 const unsigned short* __restrict__ Bt,
                                                 OUT_T* __restrict__ C, int M, int N, int K,
                                                 float ascale, int scol) {
  __shared__ alignas(16) unsigned short As[128 * 32];
  __shared__ alignas(16) unsigned short Bs[128 * 32];
  const int tid = threadIdx.x;
  const int m0 = blockIdx.y * 128, n0 = blockIdx.x * 128;
  const int lane = tid & 63, w = tid >> 6;
  const int lr = lane & 15, lg = lane >> 4;
  const int wm = w >> 1, wn = w & 1;
  f32x4 acc[4][4] = {};
  for (int k0 = 0; k0 < K; k0 += 32) {
#pragma unroll
    for (int j = 0; j < 2; ++j) {
      int ci = j * 256 + tid;
      gld16(A + (size_t)(m0 + (ci >> 2)) * K + k0 + (ci & 3) * 8, (void*)(As + ci * 8));
      gld16(Bt + (size_t)(n0 + (ci >> 2)) * K + k0 + (ci & 3) * 8, (void*)(Bs + ci * 8));
    }
    __syncthreads();
    bf16x8 af[4], bfr[4];
#pragma unroll
    for (int i = 0; i < 4; ++i) af[i] = ldsb8(As + (wm * 64 + i * 16 + lr) * 32 + lg * 8);
#pragma unroll
    for (int j = 0; j < 4; ++j) bfr[j] = ldsb8(Bs + (wn * 64 + j * 16 + lr) * 32 + lg * 8);
#pragma unroll
    for (int i = 0; i < 4; ++i)
#pragma unroll
      for (int j = 0; j < 4; ++j)
        acc[i][j] = __builtin_amdgcn_mfma_f32_16x16x32_bf16(af[i], bfr[j], acc[i][j], 0, 0, 0);
    __syncthreads();
  }
#pragma unroll
  for (int i = 0; i < 4; ++i)
#pragma unroll
    for (int j = 0; j < 4; ++j) {
      const int row = m0 + wm * 64 + i * 16 + lg * 4;
      const int col = n0 + wn * 64 + j * 16 + lr;
#pragma unroll
      for (int r = 0; r < 4; ++r) {
        float v = acc[i][j][r];
        if (col < scol) v *= ascale;
        store_c(C + (size_t)(row + r) * N + col, v);
      }
    }
}

// ---------- causal flash attention v4 ----------
// grid (32, H, B): 32 q-tiles of 64 rows per (b,h), dispatched heavy-first (LPT).
// 4 waves x 16 q-rows; KV tiles of 64, double-buffered, swizzled LDS.
// Q pre-scaled by 0.125*log2e in the QKV GEMM; softmax in exp2 domain; defer-max.
__global__ __launch_bounds__(256, 4) void k_attn4(const unsigned short* __restrict__ QKV,
                                                  const unsigned short* __restrict__ Vt,
                                                  unsigned short* __restrict__ O) {
  __shared__ alignas(16) unsigned short Ks[2][64 * 64];  // [s][d] swizzled
  __shared__ alignas(16) unsigned short Vs[2][64 * 64];  // [d][s] swizzled
  __shared__ alignas(16) unsigned short Ps[4][16 * 64];  // per-wave P [q][s] swizzled
  const int b = blockIdx.z, h = blockIdx.y;
  const int j = 31 - blockIdx.x;  // heavy blocks dispatch first
  const int q0 = j * 64;
  const int tid = threadIdx.x, lane = tid & 63, w = tid >> 6;
  const int lr = lane & 15, lg = lane >> 4;
  const int lsw = lr & 7;  // XOR key (row&7 for all our reads)
  const int qw = q0 + w * 16;
  const unsigned short* Qg = QKV + (size_t)b * TT * SQKV + h * DH;
  const unsigned short* Kg = QKV + (size_t)b * TT * SQKV + DM + h * DH;
  const unsigned short* Vg = Vt + (size_t)(b * NH + h) * DH * TT;
  unsigned short* Pw = Ps[w];

  // Q fragment (B-operand role): lane holds Q[qw+lr][c*32 + lg*8 ..] (pre-scaled)
  bf16x8 qf[2];
#pragma unroll
  for (int c = 0; c < 2; ++c)
    qf[c] = *(const bf16x8*)(Qg + (size_t)(qw + lr) * SQKV + c * 32 + lg * 8);

  f32x4 acco[4] = {};
  float mrun = -1e30f, lrun = 0.f;

  // stage one KV tile: 256 threads x 2 chunks each for K and V; source pre-swizzled
  auto stage = [&](int buf, int t) {
    const int s0 = t * 64;
#pragma unroll
    for (int cj = 0; cj < 2; ++cj) {
      const int ci = cj * 256 + tid;
      const int row = ci >> 3, cc = (ci & 7) ^ (row & 7);
      gld16(Kg + (size_t)(s0 + row) * SQKV + cc * 8, (void*)(Ks[buf] + ci * 8));
      gld16(Vg + (size_t)row * TT + s0 + cc * 8, (void*)(Vs[buf] + ci * 8));
    }
  };

  const int nt = j + 1;
  stage(0, 0);
  for (int t = 0; t < nt; ++t) {
    const int buf = t & 1;
    if (t + 1 < nt) {
      stage(buf ^ 1, t + 1);
      asm volatile("s_waitcnt vmcnt(4)" ::: "memory");  // tile t landed; t+1 in flight
    } else {
      asm volatile("s_waitcnt vmcnt(0)" ::: "memory");
    }
    __builtin_amdgcn_s_barrier();
    const unsigned short* Kb_ = Ks[buf];
    const unsigned short* Vb_ = Vs[buf];
    const int s0 = t * 64;
    // ---- S^T = K Q^T : st[ct] holds S[s=s0+ct*16+lg*4+r][q=qw+lr] (exp2 domain) ----
    f32x4 st[4] = {};
#pragma unroll
    for (int ct = 0; ct < 4; ++ct)
#pragma unroll
      for (int c = 0; c < 2; ++c) {
        bf16x8 kf = ldsb8(Kb_ + (ct * 16 + lr) * 64 + (((c * 4 + lg) ^ lsw) * 8));
        st[ct] = __builtin_amdgcn_mfma_f32_16x16x32_bf16(kf, qf[c], st[ct], 0, 0, 0);
      }
    // ---- lane-local softmax over 16 s-values (+2 shuffles across lg) ----
    float p[4][4];
    const bool diag = (s0 + 63 >= qw);
    const int qrel = qw + lr - s0;
    float mx = -1e30f;
    if (diag) {
#pragma unroll
      for (int ct = 0; ct < 4; ++ct)
#pragma unroll
        for (int r = 0; r < 4; ++r) {
          float v = st[ct][r];
          if (ct * 16 + lg * 4 + r > qrel) v = -1e30f;
          p[ct][r] = v;
          mx = fmaxf(mx, v);
        }
    } else {
#pragma unroll
      for (int ct = 0; ct < 4; ++ct)
#pragma unroll
        for (int r = 0; r < 4; ++r) {
          float v = st[ct][r];
          p[ct][r] = v;
          mx = fmaxf(mx, v);
        }
    }
    mx = fmaxf(mx, __shfl_xor(mx, 16));
    mx = fmaxf(mx, __shfl_xor(mx, 32));
    // defer-max: only rescale when the running max grew by > 11.5 (e^8 analog)
    if (!__all(mx <= mrun + 11.5f)) {
      const float mn = fmaxf(mrun, mx);
      const float aa = __builtin_exp2f(mrun - mn);
      mrun = mn;
      lrun *= aa;
      float aab[4];
#pragma unroll
      for (int r = 0; r < 4; ++r) aab[r] = __shfl(aa, lg * 4 + r);
#pragma unroll
      for (int dt = 0; dt < 4; ++dt)
#pragma unroll
        for (int r = 0; r < 4; ++r) acco[dt][r] *= aab[r];
    }
    float rs = 0.f;
#pragma unroll
    for (int ct = 0; ct < 4; ++ct)
#pragma unroll
      for (int r = 0; r < 4; ++r) {
        p[ct][r] = __builtin_exp2f(p[ct][r] - mrun);
        rs += p[ct][r];
      }
    rs += __shfl_xor(rs, 16);
    rs += __shfl_xor(rs, 32);
    lrun += rs;
    // ---- P -> per-wave LDS: row=lr, s-range ct*16+lg*4..+3, b64 writes ----
#pragma unroll
    for (int ct = 0; ct < 4; ++ct) {
      u32x2 pk;
      pk[0] = cvtpk(p[ct][0], p[ct][1]);
      pk[1] = cvtpk(p[ct][2], p[ct][3]);
      *(u32x2*)(Pw + lr * 64 + (((ct * 2 + (lg >> 1)) ^ lsw) * 8) + (lg & 1) * 4) = pk;
    }
    // ---- O += P V^T ----
    bf16x8 pf[2];
#pragma unroll
    for (int ks = 0; ks < 2; ++ks)
      pf[ks] = ldsb8(Pw + lr * 64 + (((ks * 4 + lg) ^ lsw) * 8));
#pragma unroll
    for (int dt = 0; dt < 4; ++dt)
#pragma unroll
      for (int ks = 0; ks < 2; ++ks) {
        bf16x8 vf = ldsb8(Vb_ + (dt * 16 + lr) * 64 + (((ks * 4 + lg) ^ lsw) * 8));
        acco[dt] = __builtin_amdgcn_mfma_f32_16x16x32_bf16(pf[ks], vf, acco[dt], 0, 0, 0);
      }
    __builtin_amdgcn_s_barrier();  // protect buf before next stage overwrites it
  }
  // ---- epilogue ----
  const float linv = 1.f / lrun;
  float lb[4];
#pragma unroll
  for (int r = 0; r < 4; ++r) lb[r] = __shfl(linv, lg * 4 + r);
#pragma unroll
  for (int dt = 0; dt < 4; ++dt)
#pragma unroll
    for (int r = 0; r < 4; ++r) {
      const int q = qw + lg * 4 + r;
      O[(size_t)(b * TT + q) * DM + h * DH + dt * 16 + lr] = f2bf(acco[dt][r] * lb[r]);
    }
}

extern "C" void kernel_launch(void* const* d_in, const int* in_sizes, int n_in,
                              void* d_out, int out_size, void* d_ws, size_t ws_size,
                              hipStream_t stream) {
  const float* x = (const float*)d_in[0];
  const float* wq = (const float*)d_in[1];
  const float* wk = (const float*)d_in[2];
  const float* wv = (const float*)d_in[3];
  const float* wo = (const float*)d_in[4];
  float* out = (float*)d_out;
  char* ws = (char*)d_ws;
  const size_t MB = 1u << 20;
  // ws layout (48 MB):
  unsigned short* xb = (unsigned short*)(ws);             // 8MB: x bf16; reused as attn-out
  unsigned short* wqt = (unsigned short*)(ws + 8 * MB);   // 2MB x4 contiguous: wq^T wk^T wv^T wo^T
  unsigned short* wot = (unsigned short*)(ws + 14 * MB);
  unsigned short* QKVb = (unsigned short*)(ws + 16 * MB); // 24MB: [MR][3072]
  unsigned short* Vtb = (unsigned short*)(ws + 40 * MB);  // 8MB: [B*H][64][T]

  k_cvt<<<(MR * DM) / (256 * 8), 256, 0, stream>>>(x, xb, MR * DM);
  dim3 tb(32, 8);
  k_wt4<<<dim3(32, 32, 4), tb, 0, stream>>>(wq, wk, wv, wo, wqt);
  // Q columns (col < DM) pre-scaled by 0.125*log2(e) for exp2-domain softmax
  k_gemm_nt<unsigned short><<<dim3(24, 32), 256, 0, stream>>>(xb, wqt, QKVb, MR, SQKV, DM,
                                                              0.18033688f, DM);
  k_vt<<<dim3(TT / 32, DH / 32, TB * NH), tb, 0, stream>>>(QKVb + 2 * DM, Vtb);
  k_attn4<<<dim3(32, NH, TB), 256, 0, stream>>>(QKVb, Vtb, xb);
  k_gemm_nt<float><<<dim3(8, 32), 256, 0, stream>>>(xb, wot, out, MR, DM, DM, 1.0f, 0);
}

// Round 5
// 133.641 us; speedup vs baseline: 2.2788x; 1.1663x over previous
//
#include <hip/hip_runtime.h>
#include <math.h>

#define DEV static __device__ __forceinline__

typedef __attribute__((ext_vector_type(4))) float f32x4;
typedef __attribute__((ext_vector_type(2))) unsigned u32x2;
typedef __attribute__((ext_vector_type(8))) __bf16 bf16x8;
typedef __attribute__((ext_vector_type(8))) unsigned short u16x8;
typedef __attribute__((ext_vector_type(4))) unsigned short u16x4;

constexpr int TB = 2;     // batch
constexpr int TT = 2048;  // seq len
constexpr int DM = 1024;  // model dim
constexpr int NH = 16;    // heads
constexpr int DH = 64;    // head dim
constexpr int MR = TB * TT;  // 4096 rows
constexpr int SQKV = 3 * DM; // fused QKV row stride

DEV unsigned short f2bf(float f) {
  union { float f; unsigned u; } v; v.f = f;
  return (unsigned short)((v.u + 0x7FFFu + ((v.u >> 16) & 1u)) >> 16);
}

DEV unsigned cvtpk(float a, float b) {  // lo=bf16(a), hi=bf16(b)
  unsigned r;
  asm("v_cvt_pk_bf16_f32 %0, %1, %2" : "=v"(r) : "v"(a), "v"(b));
  return r;
}

DEV void gld16(const void* g, void* l) {
  __builtin_amdgcn_global_load_lds((const __attribute__((address_space(1))) void*)g,
                                   (__attribute__((address_space(3))) void*)l, 16, 0, 0);
}

DEV bf16x8 ldsb8(const unsigned short* p) { return *(const bf16x8*)p; }

// ---------- fp32 -> bf16 convert (n multiple of 8) ----------
__global__ void k_cvt(const float* __restrict__ in, unsigned short* __restrict__ out, int n) {
  int i = (blockIdx.x * 256 + threadIdx.x) * 8;
  if (i >= n) return;
  f32x4 a = *(const f32x4*)(in + i);
  f32x4 b = *(const f32x4*)(in + i + 4);
  u16x8 o;
#pragma unroll
  for (int j = 0; j < 4; ++j) { o[j] = f2bf(a[j]); o[j + 4] = f2bf(b[j]); }
  *(u16x8*)(out + i) = o;
}

// ---------- 4 weights fp32 [K][N] -> bf16 transposed [N][K], contiguous dst ----------
__global__ void k_wt4(const float* __restrict__ w0, const float* __restrict__ w1,
                      const float* __restrict__ w2, const float* __restrict__ w3,
                      unsigned short* __restrict__ dst) {
  __shared__ float tile[32][33];
  const int z = blockIdx.z;
  const float* w = z == 0 ? w0 : z == 1 ? w1 : z == 2 ? w2 : w3;
  unsigned short* wt = dst + (size_t)z * DM * DM;
  const int k0 = blockIdx.y * 32, n0 = blockIdx.x * 32;
  const int tx = threadIdx.x, ty = threadIdx.y;  // 32 x 8
#pragma unroll
  for (int yy = 0; yy < 32; yy += 8)
    tile[ty + yy][tx] = w[(size_t)(k0 + ty + yy) * DM + n0 + tx];
  __syncthreads();
#pragma unroll
  for (int yy = 0; yy < 32; yy += 8)
    wt[(size_t)(n0 + ty + yy) * DM + k0 + tx] = f2bf(tile[tx][ty + yy]);
}

// ---------- NT GEMM: C[M][N] = A[M][K] * Bt[N][K]^T, bf16 in, fp32 acc ----------
// Columns col < scol get scaled by ascale on store (pre-scale Q).
// If vt != nullptr, columns col >= 2*DM are written to vt[bh][d][t] (V-transpose
// fused into the epilogue) instead of C.
DEV void store_c(float* p, float v) { *p = v; }
DEV void store_c(unsigned short* p, float v) { *p = f2bf(v); }

template <typename OUT_T>
__global__ __launch_bounds__(256) void k_gemm_nt(const unsigned short* __restrict__ A,
                                                 const unsigned short* __restrict__ Bt,
                                                 OUT_T* __restrict__ C, int M, int N, int K,
                                                 float ascale, int scol,
                                                 unsigned short* __restrict__ vt) {
  __shared__ alignas(16) unsigned short As[128 * 32];
  __shared__ alignas(16) unsigned short Bs[128 * 32];
  const int tid = threadIdx.x;
  const int m0 = blockIdx.y * 128, n0 = blockIdx.x * 128;
  const int lane = tid & 63, w = tid >> 6;
  const int lr = lane & 15, lg = lane >> 4;
  const int wm = w >> 1, wn = w & 1;
  f32x4 acc[4][4] = {};
  for (int k0 = 0; k0 < K; k0 += 32) {
#pragma unroll
    for (int j = 0; j < 2; ++j) {
      int ci = j * 256 + tid;
      gld16(A + (size_t)(m0 + (ci >> 2)) * K + k0 + (ci & 3) * 8, (void*)(As + ci * 8));
      gld16(Bt + (size_t)(n0 + (ci >> 2)) * K + k0 + (ci & 3) * 8, (void*)(Bs + ci * 8));
    }
    __syncthreads();
    bf16x8 af[4], bfr[4];
#pragma unroll
    for (int i = 0; i < 4; ++i) af[i] = ldsb8(As + (wm * 64 + i * 16 + lr) * 32 + lg * 8);
#pragma unroll
    for (int j = 0; j < 4; ++j) bfr[j] = ldsb8(Bs + (wn * 64 + j * 16 + lr) * 32 + lg * 8);
#pragma unroll
    for (int i = 0; i < 4; ++i)
#pragma unroll
      for (int j = 0; j < 4; ++j)
        acc[i][j] = __builtin_amdgcn_mfma_f32_16x16x32_bf16(af[i], bfr[j], acc[i][j], 0, 0, 0);
    __syncthreads();
  }
#pragma unroll
  for (int i = 0; i < 4; ++i)
#pragma unroll
    for (int j = 0; j < 4; ++j) {
      const int row = m0 + wm * 64 + i * 16 + lg * 4;
      const int col = n0 + wn * 64 + j * 16 + lr;
      if (vt && col >= 2 * DM) {
        // V output -> Vt[(b*NH+h)*DH + d][t], 4 consecutive t per lane, 8B store
        const int hh = (col - 2 * DM) >> 6, dd = (col - 2 * DM) & 63;
        const int bb = row >> 11, tt = row & (TT - 1);
        u16x4 pk;
#pragma unroll
        for (int r = 0; r < 4; ++r) pk[r] = f2bf(acc[i][j][r]);
        *(u16x4*)(vt + (size_t)((bb * NH + hh) * DH + dd) * TT + tt) = pk;
      } else {
#pragma unroll
        for (int r = 0; r < 4; ++r) {
          float v = acc[i][j][r];
          if (col < scol) v *= ascale;
          store_c(C + (size_t)(row + r) * N + col, v);
        }
      }
    }
}

// ---------- causal flash attention v5 ----------
// grid(1024) 1-D: decode (bh, j) so that each CU's 4 blocks (n, n+256, n+512,
// n+768 share a CU under 8-XCD round-robin) sum to exactly 66 tile-units.
// 4 waves x 16 q-rows; KV tiles of 64, double-buffered, swizzled LDS.
// Q pre-scaled by 0.125*log2e in the QKV GEMM; softmax in exp2 domain; defer-max.
__global__ __launch_bounds__(256, 4) void k_attn5(const unsigned short* __restrict__ QKV,
                                                  const unsigned short* __restrict__ Vt,
                                                  unsigned short* __restrict__ O) {
  __shared__ alignas(16) unsigned short Ks[2][64 * 64];  // [s][d] swizzled
  __shared__ alignas(16) unsigned short Vs[2][64 * 64];  // [d][s] swizzled
  __shared__ alignas(16) unsigned short Ps[4][16 * 64];  // per-wave P [q][s] swizzled
  // balanced decode: pairs (pi, 31-pi) -> per-CU work == 66 units for all CUs
  const int id = blockIdx.x;
  const int c = id & 255, r4 = id >> 8;
  const int pairIdx = (c << 1) | (r4 >> 1);
  const int bh = pairIdx >> 4, pi = pairIdx & 15;
  const int j = (r4 & 1) ? (31 - pi) : pi;
  const int b = bh >> 4, h = bh & 15;
  const int q0 = j * 64;
  const int tid = threadIdx.x, lane = tid & 63, w = tid >> 6;
  const int lr = lane & 15, lg = lane >> 4;
  const int lsw = lr & 7;  // XOR key (row&7 for all our reads)
  const int qw = q0 + w * 16;
  const unsigned short* Qg = QKV + (size_t)b * TT * SQKV + h * DH;
  const unsigned short* Kg = QKV + (size_t)b * TT * SQKV + DM + h * DH;
  const unsigned short* Vg = Vt + (size_t)(b * NH + h) * DH * TT;
  unsigned short* Pw = Ps[w];

  // Q fragment (B-operand role): lane holds Q[qw+lr][c*32 + lg*8 ..] (pre-scaled)
  bf16x8 qf[2];
#pragma unroll
  for (int c2 = 0; c2 < 2; ++c2)
    qf[c2] = *(const bf16x8*)(Qg + (size_t)(qw + lr) * SQKV + c2 * 32 + lg * 8);

  f32x4 acco[4] = {};
  float mrun = -1e30f, lrun = 0.f;

  // stage one KV tile: 256 threads x 2 chunks each for K and V; source pre-swizzled
  auto stage = [&](int buf, int t) {
    const int s0 = t * 64;
#pragma unroll
    for (int cj = 0; cj < 2; ++cj) {
      const int ci = cj * 256 + tid;
      const int row = ci >> 3, cc = (ci & 7) ^ (row & 7);
      gld16(Kg + (size_t)(s0 + row) * SQKV + cc * 8, (void*)(Ks[buf] + ci * 8));
      gld16(Vg + (size_t)row * TT + s0 + cc * 8, (void*)(Vs[buf] + ci * 8));
    }
  };

  const int nt = j + 1;
  stage(0, 0);
  for (int t = 0; t < nt; ++t) {
    const int buf = t & 1;
    if (t + 1 < nt) {
      stage(buf ^ 1, t + 1);
      asm volatile("s_waitcnt vmcnt(4)" ::: "memory");  // tile t landed; t+1 in flight
    } else {
      asm volatile("s_waitcnt vmcnt(0)" ::: "memory");
    }
    __builtin_amdgcn_s_barrier();
    const unsigned short* Kb_ = Ks[buf];
    const unsigned short* Vb_ = Vs[buf];
    const int s0 = t * 64;
    // ---- S^T = K Q^T : st[ct] holds S[s=s0+ct*16+lg*4+r][q=qw+lr] (exp2 domain) ----
    f32x4 st[4] = {};
#pragma unroll
    for (int ct = 0; ct < 4; ++ct)
#pragma unroll
      for (int c2 = 0; c2 < 2; ++c2) {
        bf16x8 kf = ldsb8(Kb_ + (ct * 16 + lr) * 64 + (((c2 * 4 + lg) ^ lsw) * 8));
        st[ct] = __builtin_amdgcn_mfma_f32_16x16x32_bf16(kf, qf[c2], st[ct], 0, 0, 0);
      }
    // ---- lane-local softmax over 16 s-values (+2 shuffles across lg) ----
    float p[4][4];
    const bool diag = (s0 + 63 >= qw);
    const int qrel = qw + lr - s0;
    float mx = -1e30f;
    if (diag) {
#pragma unroll
      for (int ct = 0; ct < 4; ++ct)
#pragma unroll
        for (int r = 0; r < 4; ++r) {
          float v = st[ct][r];
          if (ct * 16 + lg * 4 + r > qrel) v = -1e30f;
          p[ct][r] = v;
          mx = fmaxf(mx, v);
        }
    } else {
#pragma unroll
      for (int ct = 0; ct < 4; ++ct)
#pragma unroll
        for (int r = 0; r < 4; ++r) {
          float v = st[ct][r];
          p[ct][r] = v;
          mx = fmaxf(mx, v);
        }
    }
    mx = fmaxf(mx, __shfl_xor(mx, 16));
    mx = fmaxf(mx, __shfl_xor(mx, 32));
    // defer-max: only rescale when the running max grew by > 11.5 (e^8 analog)
    if (!__all(mx <= mrun + 11.5f)) {
      const float mn = fmaxf(mrun, mx);
      const float aa = __builtin_exp2f(mrun - mn);
      mrun = mn;
      lrun *= aa;
      float aab[4];
#pragma unroll
      for (int r = 0; r < 4; ++r) aab[r] = __shfl(aa, lg * 4 + r);
#pragma unroll
      for (int dt = 0; dt < 4; ++dt)
#pragma unroll
        for (int r = 0; r < 4; ++r) acco[dt][r] *= aab[r];
    }
    float rs = 0.f;
#pragma unroll
    for (int ct = 0; ct < 4; ++ct)
#pragma unroll
      for (int r = 0; r < 4; ++r) {
        p[ct][r] = __builtin_exp2f(p[ct][r] - mrun);
        rs += p[ct][r];
      }
    rs += __shfl_xor(rs, 16);
    rs += __shfl_xor(rs, 32);
    lrun += rs;
    // ---- P -> per-wave LDS: row=lr, s-range ct*16+lg*4..+3, b64 writes ----
#pragma unroll
    for (int ct = 0; ct < 4; ++ct) {
      u32x2 pk;
      pk[0] = cvtpk(p[ct][0], p[ct][1]);
      pk[1] = cvtpk(p[ct][2], p[ct][3]);
      *(u32x2*)(Pw + lr * 64 + (((ct * 2 + (lg >> 1)) ^ lsw) * 8) + (lg & 1) * 4) = pk;
    }
    // ---- O += P V^T ----
    bf16x8 pf[2];
#pragma unroll
    for (int ks = 0; ks < 2; ++ks)
      pf[ks] = ldsb8(Pw + lr * 64 + (((ks * 4 + lg) ^ lsw) * 8));
#pragma unroll
    for (int dt = 0; dt < 4; ++dt)
#pragma unroll
      for (int ks = 0; ks < 2; ++ks) {
        bf16x8 vf = ldsb8(Vb_ + (dt * 16 + lr) * 64 + (((ks * 4 + lg) ^ lsw) * 8));
        acco[dt] = __builtin_amdgcn_mfma_f32_16x16x32_bf16(pf[ks], vf, acco[dt], 0, 0, 0);
      }
    __builtin_amdgcn_s_barrier();  // protect buf before next stage overwrites it
  }
  // ---- epilogue ----
  const float linv = 1.f / lrun;
  float lb[4];
#pragma unroll
  for (int r = 0; r < 4; ++r) lb[r] = __shfl(linv, lg * 4 + r);
#pragma unroll
  for (int dt = 0; dt < 4; ++dt)
#pragma unroll
    for (int r = 0; r < 4; ++r) {
      const int q = qw + lg * 4 + r;
      O[(size_t)(b * TT + q) * DM + h * DH + dt * 16 + lr] = f2bf(acco[dt][r] * lb[r]);
    }
}

extern "C" void kernel_launch(void* const* d_in, const int* in_sizes, int n_in,
                              void* d_out, int out_size, void* d_ws, size_t ws_size,
                              hipStream_t stream) {
  const float* x = (const float*)d_in[0];
  const float* wq = (const float*)d_in[1];
  const float* wk = (const float*)d_in[2];
  const float* wv = (const float*)d_in[3];
  const float* wo = (const float*)d_in[4];
  float* out = (float*)d_out;
  char* ws = (char*)d_ws;
  const size_t MB = 1u << 20;
  // ws layout (48 MB):
  unsigned short* xb = (unsigned short*)(ws);             // 8MB: x bf16; reused as attn-out
  unsigned short* wqt = (unsigned short*)(ws + 8 * MB);   // 2MB x4 contiguous: wq^T wk^T wv^T wo^T
  unsigned short* wot = (unsigned short*)(ws + 14 * MB);
  unsigned short* QKVb = (unsigned short*)(ws + 16 * MB); // 24MB: [MR][3072] (V region unused)
  unsigned short* Vtb = (unsigned short*)(ws + 40 * MB);  // 8MB: [B*H][64][T]

  k_cvt<<<(MR * DM) / (256 * 8), 256, 0, stream>>>(x, xb, MR * DM);
  dim3 tb(32, 8);
  k_wt4<<<dim3(32, 32, 4), tb, 0, stream>>>(wq, wk, wv, wo, wqt);
  // Q columns (col < DM) pre-scaled by 0.125*log2(e); V columns written to Vtb
  k_gemm_nt<unsigned short><<<dim3(24, 32), 256, 0, stream>>>(xb, wqt, QKVb, MR, SQKV, DM,
                                                              0.18033688f, DM, Vtb);
  k_attn5<<<dim3(1024), 256, 0, stream>>>(QKVb, Vtb, xb);
  k_gemm_nt<float><<<dim3(8, 32), 256, 0, stream>>>(xb, wot, out, MR, DM, DM, 1.0f, 0, nullptr);
}